// Round 5
// baseline (262.719 us; speedup 1.0000x reference)
//
#include <hip/hip_runtime.h>
#include <hip/hip_bf16.h>
#include <cmath>

#define NB 4
#define NM 32
#define DKc 256
#define DVc 32
#define NP 4096

using bf16x8 = __attribute__((ext_vector_type(8))) short;
using f32x4  = __attribute__((ext_vector_type(4))) float;
using f32x2  = __attribute__((ext_vector_type(2))) float;

__device__ __forceinline__ unsigned short f2bf(float f) {
    union { float f; unsigned u; } x; x.f = f;
    unsigned r = 0x7FFFu + ((x.u >> 16) & 1u);
    return (unsigned short)((x.u + r) >> 16);
}

// ---------------- k_prep: fc transpose (1024 blocks) + W transposes (32) + vproj (64) ----------------
__global__ __launch_bounds__(256) void k_prep(
    const float* __restrict__ fc, unsigned short* __restrict__ fcT,
    const float* __restrict__ Q, unsigned short* __restrict__ WTq,
    const float* __restrict__ K, unsigned short* __restrict__ WTk,
    const float* __restrict__ fm, const float* __restrict__ V, float* __restrict__ vproj) {
    int x = blockIdx.x;
    int t = threadIdx.x;
    if (x < 1056) {
        __shared__ float tile[64][65];
        const float* s; unsigned short* d; int R, C, r0, c0;
        if (x < 1024) {
            int bb = x >> 8, rest = x & 255;
            R = 256; C = 4096;
            r0 = (rest >> 6) * 64; c0 = (rest & 63) * 64;
            s = fc + (long)bb * 256 * 4096; d = fcT + (long)bb * 256 * 4096;
        } else {
            int i = x - 1024;
            int mat = i >> 4, idx = i & 15;
            R = 256; C = 256;
            r0 = (idx >> 2) * 64; c0 = (idx & 3) * 64;
            s = mat ? K : Q; d = mat ? WTk : WTq;
        }
        #pragma unroll
        for (int j = 0; j < 16; ++j) {
            int i = t + 256 * j;
            int r = i >> 6, c = i & 63;
            tile[r][c] = s[(long)(r0 + r) * C + c0 + c];
        }
        __syncthreads();
        #pragma unroll
        for (int j = 0; j < 8; ++j) {
            int i = t + 256 * j;
            int row = i >> 5;
            int pr = i & 31;
            float f0 = tile[2 * pr][row];
            float f1 = tile[2 * pr + 1][row];
            unsigned pack = (unsigned)f2bf(f0) | ((unsigned)f2bf(f1) << 16);
            reinterpret_cast<unsigned*>(d)[(((long)(c0 + row) * R + r0) >> 1) + pr] = pack;
        }
    } else {
        __shared__ float Vl[32][32];
        __shared__ float fml[32][256];
        int i = x - 1056;
        int b = i >> 4, p0 = (i & 15) * 256;
        #pragma unroll
        for (int j = 0; j < 4; ++j) { int ii = t + 256 * j; Vl[ii >> 5][ii & 31] = V[ii]; }
        for (int j = 0; j < 32; ++j) {
            int ii = t + 256 * j;
            int dd = ii >> 8, c = ii & 255;
            fml[dd][c] = fm[((long)b * DVc + dd) * NP + p0 + c];
        }
        __syncthreads();
        float acc[32];
        #pragma unroll
        for (int e = 0; e < 32; ++e) acc[e] = 0.f;
        for (int dd = 0; dd < 32; ++dd) {
            float fv = fml[dd][t];
            #pragma unroll
            for (int e = 0; e < 32; ++e) acc[e] += fv * Vl[dd][e];
        }
        #pragma unroll
        for (int e = 0; e < 32; ++e) vproj[((long)b * DVc + e) * NP + p0 + t] = acc[e];
    }
}

// ---------------- k_proj: full-e (256) per 32-p tile. grid (128, 8=b*mat) = 1024 blocks ----------------
__global__ __launch_bounds__(256) void k_proj(
    const unsigned short* __restrict__ WTq, const unsigned short* __restrict__ WTk,
    const unsigned short* __restrict__ fcT,
    float* __restrict__ qproj, float* __restrict__ kproj) {
    int t = threadIdx.x;
    int wave = t >> 6, lane = t & 63;
    int y = blockIdx.y;
    int b = y & 3, mat = y >> 2;
    int p0 = blockIdx.x * 32;
    int ln = lane & 15, quad = lane >> 4;
    const unsigned short* WT = mat ? WTk : WTq;
    float* dst = mat ? kproj : qproj;
    int e0w = wave * 64;
    const unsigned short* bbase = fcT + ((long)b * NP + p0 + ln) * DKc + quad * 8;
    f32x4 acc[4][2] = {};
    for (int kk = 0; kk < DKc; kk += 32) {
        bf16x8 a[4], bb[2];
        #pragma unroll
        for (int i = 0; i < 4; ++i)
            a[i] = *reinterpret_cast<const bf16x8*>(WT + (long)(e0w + i * 16 + ln) * DKc + quad * 8 + kk);
        #pragma unroll
        for (int j = 0; j < 2; ++j)
            bb[j] = *reinterpret_cast<const bf16x8*>(bbase + (long)j * 16 * DKc + kk);
        #pragma unroll
        for (int i = 0; i < 4; ++i)
            #pragma unroll
            for (int j = 0; j < 2; ++j)
                acc[i][j] = __builtin_amdgcn_mfma_f32_16x16x32_bf16(a[i], bb[j], acc[i][j], 0, 0, 0);
    }
    #pragma unroll
    for (int i = 0; i < 4; ++i)
        #pragma unroll
        for (int j = 0; j < 2; ++j)
            #pragma unroll
            for (int r = 0; r < 4; ++r) {
                int e = e0w + i * 16 + quad * 4 + r, p = p0 + j * 16 + ln;
                dst[((long)b * DKc + e) * NP + p] = acc[i][j][r];
            }
}

// ---------------- k_fused: scores + softmax(w) + ctx + epilogue, one pass ----------------
// grid 256 (b*64+hrow), 1024 thr (16 waves).
// Round-4 post-mortem: VGPR_Count=32 proved hipcc collapsed the 8-deep load
// batch into load->use pairs (latency-bound, ~2 loads in flight). Fix: register
// double-buffer + sched_barrier(0) fence between [next-batch loads] and
// [current-batch FMAs] so 8-16 f32x4 loads stay in flight (counted vmcnt).
__global__ __launch_bounds__(1024) void k_fused(
    const float* __restrict__ qproj, const float* __restrict__ kproj,
    const float* __restrict__ kbuf, const float* __restrict__ vproj,
    const float* __restrict__ vbuf, const float* __restrict__ fm,
    float* __restrict__ out, float scale) {
    __shared__ float smem[16384];              // 65536 B
    int t = threadIdx.x;
    int b = blockIdx.x >> 6, hrow = blockIdx.x & 63;
    int p0 = hrow * 64;
    int wave = t >> 6, lane = t & 63;
    int wg = lane & 15;

    // phase 1: stage q[b][e][p0..p0+63] -> smem[e*64 + w], f32x4 per lane
    {
        const float* qbase = qproj + (long)b * DKc * NP + p0;
        #pragma unroll
        for (int j = 0; j < 4; ++j) {
            int i = t + 1024 * j;              // [0,4096)
            int e = i >> 4, g = i & 15;
            *reinterpret_cast<f32x4*>(&smem[e * 64 + g * 4]) =
                *reinterpret_cast<const f32x4*>(qbase + (long)e * NP + g * 4);
        }
    }
    __syncthreads();

    // phase 2: scores. wave=(eh=wave>>3, mq=wave&7); lane=(mi=lane>>4, wg).
    // m = mq*4+mi. e in [eh*128, eh*128+128). Register-dbuf pipeline.
    {
        int mi = lane >> 4;
        int eh = wave >> 3, mq = wave & 7;
        int m = mq * 4 + mi;
        const float* kbase = (mq == 0 ? kproj + (long)m * DKc * NP
                                      : kbuf + (long)(m - 4) * DKc * NP)
                             + (long)(eh * 128) * NP + p0 + wg * 4;
        const float* qb = &smem[(eh * 128) * 64 + wg * 4];
        f32x4 s4 = {0.f, 0.f, 0.f, 0.f};
        f32x4 kv[8], kn[8];
        #pragma unroll
        for (int u = 0; u < 8; ++u)
            kv[u] = *reinterpret_cast<const f32x4*>(kbase + (long)u * NP);
        #pragma unroll
        for (int e8 = 0; e8 < 128; e8 += 8) {
            if (e8 + 8 < 128) {                 // folds at compile time (full unroll)
                #pragma unroll
                for (int u = 0; u < 8; ++u)
                    kn[u] = *reinterpret_cast<const f32x4*>(kbase + (long)(e8 + 8 + u) * NP);
            }
            __builtin_amdgcn_sched_barrier(0);  // loads stay above; FMAs stay below
            #pragma unroll
            for (int u = 0; u < 8; ++u) {
                f32x4 qv = *reinterpret_cast<const f32x4*>(qb + (e8 + u) * 64);
                s4 += qv * kv[u];
            }
            #pragma unroll
            for (int u = 0; u < 8; ++u) kv[u] = kn[u];   // SSA-renamed away by unroll
        }
        __syncthreads();                       // all q reads retired -> region reusable
        // partial scores: smem[eh*2048 + m*64 + w]
        *reinterpret_cast<f32x4*>(&smem[eh * 2048 + m * 64 + wg * 4]) = s4;
    }
    __syncthreads();

    // softmax over w: wave handles 2 m rows; lane = w. attn -> smem[4096 + m*64 + w]
    #pragma unroll
    for (int r = 0; r < 2; ++r) {
        int m = wave * 2 + r;
        float x = (smem[m * 64 + lane] + smem[2048 + m * 64 + lane]) * scale;
        float mx = x;
        #pragma unroll
        for (int dd = 1; dd < 64; dd <<= 1) mx = fmaxf(mx, __shfl_xor(mx, dd));
        float ev = __expf(x - mx);
        float sum = ev;
        #pragma unroll
        for (int dd = 1; dd < 64; dd <<= 1) sum += __shfl_xor(sum, dd);
        smem[4096 + m * 64 + lane] = ev / sum;
    }
    __syncthreads();

    // phase 3: ctx. wave=(mh=wave>>3, dq=wave&7); lane=(di=lane>>4, wg).
    // d = dq*4+di; accumulate over m in [mh*16, mh*16+16). All 16 v loads
    // issued before any FMA (fenced) -> full MLP on the 256 KB v stream.
    {
        int di = lane >> 4;
        int mh = wave >> 3, dq = wave & 7;
        int dd = dq * 4 + di;
        f32x4 vv[16];
        #pragma unroll
        for (int mm = 0; mm < 16; ++mm) {
            int m = mh * 16 + mm;
            const float* vb_ = (m < 4 ? vproj + (long)m * DVc * NP
                                      : vbuf + (long)(m - 4) * DVc * NP);
            vv[mm] = *reinterpret_cast<const f32x4*>(vb_ + (long)dd * NP + p0 + wg * 4);
        }
        __builtin_amdgcn_sched_barrier(0);
        f32x4 c4 = {0.f, 0.f, 0.f, 0.f};
        #pragma unroll
        for (int mm = 0; mm < 16; ++mm) {
            int m = mh * 16 + mm;
            f32x4 a4 = *reinterpret_cast<const f32x4*>(&smem[4096 + m * 64 + wg * 4]);
            c4 += a4 * vv[mm];
        }
        // ctx partial: smem[mh*2048 + d*64 + w] (partials region is dead)
        *reinterpret_cast<f32x4*>(&smem[mh * 2048 + dd * 64 + wg * 4]) = c4;
    }
    __syncthreads();

    // final: 2048 outputs / 1024 threads
    #pragma unroll
    for (int r = 0; r < 2; ++r) {
        int i = t + 1024 * r;
        int dd = i >> 6, w = i & 63;
        float c = smem[dd * 64 + w] + smem[2048 + dd * 64 + w];
        long gi = ((long)b * DVc + dd) * NP + p0 + w;
        out[gi] = fm[gi] + 0.5f * c;
    }
}

extern "C" void kernel_launch(void* const* d_in, const int* in_sizes, int n_in,
                              void* d_out, int out_size, void* d_ws, size_t ws_size,
                              hipStream_t stream) {
    const float* fc = (const float*)d_in[0];
    const float* fm = (const float*)d_in[1];
    const float* kb = (const float*)d_in[2];
    const float* vb = (const float*)d_in[3];
    const float* Q  = (const float*)d_in[4];
    const float* K  = (const float*)d_in[5];
    const float* V  = (const float*)d_in[6];
    float* out = (float*)d_out;
    char* ws = (char*)d_ws;
    // layout: qproj/kproj/vproj persistent; fcT+WT dead after k_proj.
    float*          qproj = (float*)(ws);                          // 16777216 B
    float*          kproj = (float*)(ws + 16777216);               // 16777216 B
    float*          vproj = (float*)(ws + 33554432);               //  2097152 B
    unsigned short* fcT   = (unsigned short*)(ws + 35651584);      //  8388608 B
    unsigned short* WTq   = (unsigned short*)(ws + 44040192);      //   131072 B
    unsigned short* WTk   = (unsigned short*)(ws + 44171264);      //   131072 B
    float scale = (float)(log(135168.0) / log(1000.0) / 16.0);

    hipLaunchKernelGGL(k_prep, dim3(1120), dim3(256), 0, stream,
                       fc, fcT, Q, WTq, K, WTk, fm, V, vproj);
    hipLaunchKernelGGL(k_proj, dim3(128, 8), dim3(256), 0, stream,
                       WTq, WTk, fcT, qproj, kproj);
    hipLaunchKernelGGL(k_fused, dim3(256), dim3(1024), 0, stream,
                       qproj, kproj, kb, vproj, vb, fm, out, scale);
}

// Round 6
// 252.394 us; speedup vs baseline: 1.0409x; 1.0409x over previous
//
#include <hip/hip_runtime.h>
#include <hip/hip_bf16.h>
#include <cmath>

#define NB 4
#define NM 32
#define DKc 256
#define DVc 32
#define NP 4096

using bf16x8 = __attribute__((ext_vector_type(8))) short;
using f32x4  = __attribute__((ext_vector_type(4))) float;
using f32x2  = __attribute__((ext_vector_type(2))) float;

__device__ __forceinline__ unsigned short f2bf(float f) {
    union { float f; unsigned u; } x; x.f = f;
    unsigned r = 0x7FFFu + ((x.u >> 16) & 1u);
    return (unsigned short)((x.u + r) >> 16);
}

// ---------------- k_prep: fc transpose (1024 blocks) + W transposes (32) + vproj (64) ----------------
__global__ __launch_bounds__(256) void k_prep(
    const float* __restrict__ fc, unsigned short* __restrict__ fcT,
    const float* __restrict__ Q, unsigned short* __restrict__ WTq,
    const float* __restrict__ K, unsigned short* __restrict__ WTk,
    const float* __restrict__ fm, const float* __restrict__ V, float* __restrict__ vproj) {
    int x = blockIdx.x;
    int t = threadIdx.x;
    if (x < 1056) {
        __shared__ float tile[64][65];
        const float* s; unsigned short* d; int R, C, r0, c0;
        if (x < 1024) {
            int bb = x >> 8, rest = x & 255;
            R = 256; C = 4096;
            r0 = (rest >> 6) * 64; c0 = (rest & 63) * 64;
            s = fc + (long)bb * 256 * 4096; d = fcT + (long)bb * 256 * 4096;
        } else {
            int i = x - 1024;
            int mat = i >> 4, idx = i & 15;
            R = 256; C = 256;
            r0 = (idx >> 2) * 64; c0 = (idx & 3) * 64;
            s = mat ? K : Q; d = mat ? WTk : WTq;
        }
        #pragma unroll
        for (int j = 0; j < 16; ++j) {
            int i = t + 256 * j;
            int r = i >> 6, c = i & 63;
            tile[r][c] = s[(long)(r0 + r) * C + c0 + c];
        }
        __syncthreads();
        #pragma unroll
        for (int j = 0; j < 8; ++j) {
            int i = t + 256 * j;
            int row = i >> 5;
            int pr = i & 31;
            float f0 = tile[2 * pr][row];
            float f1 = tile[2 * pr + 1][row];
            unsigned pack = (unsigned)f2bf(f0) | ((unsigned)f2bf(f1) << 16);
            reinterpret_cast<unsigned*>(d)[(((long)(c0 + row) * R + r0) >> 1) + pr] = pack;
        }
    } else {
        __shared__ float Vl[32][32];
        __shared__ float fml[32][256];
        int i = x - 1056;
        int b = i >> 4, p0 = (i & 15) * 256;
        #pragma unroll
        for (int j = 0; j < 4; ++j) { int ii = t + 256 * j; Vl[ii >> 5][ii & 31] = V[ii]; }
        for (int j = 0; j < 32; ++j) {
            int ii = t + 256 * j;
            int dd = ii >> 8, c = ii & 255;
            fml[dd][c] = fm[((long)b * DVc + dd) * NP + p0 + c];
        }
        __syncthreads();
        float acc[32];
        #pragma unroll
        for (int e = 0; e < 32; ++e) acc[e] = 0.f;
        for (int dd = 0; dd < 32; ++dd) {
            float fv = fml[dd][t];
            #pragma unroll
            for (int e = 0; e < 32; ++e) acc[e] += fv * Vl[dd][e];
        }
        #pragma unroll
        for (int e = 0; e < 32; ++e) vproj[((long)b * DVc + e) * NP + p0 + t] = acc[e];
    }
}

// ---------------- k_proj: full-e (256) per 64-p tile. grid (64, 8=b*mat) — round-2 version ----------------
__global__ __launch_bounds__(256) void k_proj(
    const unsigned short* __restrict__ WTq, const unsigned short* __restrict__ WTk,
    const unsigned short* __restrict__ fcT,
    float* __restrict__ qproj, float* __restrict__ kproj) {
    int t = threadIdx.x;
    int wave = t >> 6, lane = t & 63;
    int y = blockIdx.y;
    int b = y & 3, mat = y >> 2;
    int p0 = blockIdx.x * 64;
    int ln = lane & 15, quad = lane >> 4;
    const unsigned short* WT = mat ? WTk : WTq;
    float* dst = mat ? kproj : qproj;
    int e0w = wave * 64;
    const unsigned short* bbase = fcT + ((long)b * NP + p0 + ln) * DKc + quad * 8;
    f32x4 acc[4][4] = {};
    for (int kk = 0; kk < DKc; kk += 32) {
        bf16x8 a[4], bb[4];
        #pragma unroll
        for (int i = 0; i < 4; ++i)
            a[i] = *reinterpret_cast<const bf16x8*>(WT + (long)(e0w + i * 16 + ln) * DKc + quad * 8 + kk);
        #pragma unroll
        for (int j = 0; j < 4; ++j)
            bb[j] = *reinterpret_cast<const bf16x8*>(bbase + (long)j * 16 * DKc + kk);
        #pragma unroll
        for (int i = 0; i < 4; ++i)
            #pragma unroll
            for (int j = 0; j < 4; ++j)
                acc[i][j] = __builtin_amdgcn_mfma_f32_16x16x32_bf16(a[i], bb[j], acc[i][j], 0, 0, 0);
    }
    #pragma unroll
    for (int i = 0; i < 4; ++i)
        #pragma unroll
        for (int j = 0; j < 4; ++j)
            #pragma unroll
            for (int r = 0; r < 4; ++r) {
                int e = e0w + i * 16 + quad * 4 + r, p = p0 + j * 16 + ln;
                dst[((long)b * DKc + e) * NP + p] = acc[i][j][r];
            }
}

// ---------------- k_fused: asm-pipelined scores + softmax(w) + ctx + epilogue ----------------
// grid 256 (b*64+hrow), 1024 thr (wave = es = e-sixteenth, lane = w).
// Score loop: 32 hand-unrolled m-stages; 16 asm global_load_dword per stage into
// alternating kA/kB, counted s_waitcnt vmcnt(16) (NEVER 0 in steady state) +
// sched_barrier(0) fence (rule #18), FMAs in C. 16-32 loads in flight per wave.
// No compiler vmem in the counted window (q also asm-loaded; acc/qr in regs).
// LDS only for: es-partial fold [8][32][64] f32 (64 KB), attn, ctx partials.
#define LD16(K0, VO, BASE) do { unsigned _tv = (VO); asm volatile( \
    "global_load_dword %0, %16, %17\n\t"  "v_add_u32 %16, 0x4000, %16\n\t" \
    "global_load_dword %1, %16, %17\n\t"  "v_add_u32 %16, 0x4000, %16\n\t" \
    "global_load_dword %2, %16, %17\n\t"  "v_add_u32 %16, 0x4000, %16\n\t" \
    "global_load_dword %3, %16, %17\n\t"  "v_add_u32 %16, 0x4000, %16\n\t" \
    "global_load_dword %4, %16, %17\n\t"  "v_add_u32 %16, 0x4000, %16\n\t" \
    "global_load_dword %5, %16, %17\n\t"  "v_add_u32 %16, 0x4000, %16\n\t" \
    "global_load_dword %6, %16, %17\n\t"  "v_add_u32 %16, 0x4000, %16\n\t" \
    "global_load_dword %7, %16, %17\n\t"  "v_add_u32 %16, 0x4000, %16\n\t" \
    "global_load_dword %8, %16, %17\n\t"  "v_add_u32 %16, 0x4000, %16\n\t" \
    "global_load_dword %9, %16, %17\n\t"  "v_add_u32 %16, 0x4000, %16\n\t" \
    "global_load_dword %10, %16, %17\n\t" "v_add_u32 %16, 0x4000, %16\n\t" \
    "global_load_dword %11, %16, %17\n\t" "v_add_u32 %16, 0x4000, %16\n\t" \
    "global_load_dword %12, %16, %17\n\t" "v_add_u32 %16, 0x4000, %16\n\t" \
    "global_load_dword %13, %16, %17\n\t" "v_add_u32 %16, 0x4000, %16\n\t" \
    "global_load_dword %14, %16, %17\n\t" "v_add_u32 %16, 0x4000, %16\n\t" \
    "global_load_dword %15, %16, %17" \
    : "=&v"(K0[0]), "=&v"(K0[1]), "=&v"(K0[2]), "=&v"(K0[3]), \
      "=&v"(K0[4]), "=&v"(K0[5]), "=&v"(K0[6]), "=&v"(K0[7]), \
      "=&v"(K0[8]), "=&v"(K0[9]), "=&v"(K0[10]), "=&v"(K0[11]), \
      "=&v"(K0[12]), "=&v"(K0[13]), "=&v"(K0[14]), "=&v"(K0[15]), \
      "+v"(_tv) \
    : "s"(BASE) : "memory"); } while (0)

#define KWAIT16 do { asm volatile("s_waitcnt vmcnt(16)" ::: "memory"); \
                     __builtin_amdgcn_sched_barrier(0); } while (0)
#define KWAIT0  do { asm volatile("s_waitcnt vmcnt(0)"  ::: "memory"); \
                     __builtin_amdgcn_sched_barrier(0); } while (0)

#define FMA16(M, KV) do { \
    acc[M] = fmaf(qr[0],  KV[0],  acc[M]); acc[M] = fmaf(qr[1],  KV[1],  acc[M]); \
    acc[M] = fmaf(qr[2],  KV[2],  acc[M]); acc[M] = fmaf(qr[3],  KV[3],  acc[M]); \
    acc[M] = fmaf(qr[4],  KV[4],  acc[M]); acc[M] = fmaf(qr[5],  KV[5],  acc[M]); \
    acc[M] = fmaf(qr[6],  KV[6],  acc[M]); acc[M] = fmaf(qr[7],  KV[7],  acc[M]); \
    acc[M] = fmaf(qr[8],  KV[8],  acc[M]); acc[M] = fmaf(qr[9],  KV[9],  acc[M]); \
    acc[M] = fmaf(qr[10], KV[10], acc[M]); acc[M] = fmaf(qr[11], KV[11], acc[M]); \
    acc[M] = fmaf(qr[12], KV[12], acc[M]); acc[M] = fmaf(qr[13], KV[13], acc[M]); \
    acc[M] = fmaf(qr[14], KV[14], acc[M]); acc[M] = fmaf(qr[15], KV[15], acc[M]); \
  } while (0)

#define KBASE(M) ((M) < 4 ? kproj + (size_t)(M) * KMS : kbuf + (size_t)((M) - 4) * KMS)
#define STG(M, KV) KWAIT16; FMA16(M, KV); LD16(KV, vo, KBASE((M) + 2));

__global__ __launch_bounds__(1024) void k_fused(
    const float* __restrict__ qproj, const float* __restrict__ kproj,
    const float* __restrict__ kbuf, const float* __restrict__ vproj,
    const float* __restrict__ vbuf, const float* __restrict__ fm,
    float* __restrict__ out, float scale) {
    __shared__ float smem[16384];              // 65536 B
    int t = threadIdx.x;
    int b = blockIdx.x >> 6, hrow = blockIdx.x & 63;
    int p0 = hrow * 64;
    int wave = t >> 6, lane = t & 63;
    int wg = lane & 15;

    const size_t KMS = (size_t)DKc * NP;       // 1 MB of floats per m-slab
    float qr[16], kA[16], kB[16], acc[32];
    #pragma unroll
    for (int m = 0; m < 32; ++m) acc[m] = 0.f;

    // per-lane byte voffset for (e = wave*16 + j, p = p0 + lane); e-step = 16 KB
    unsigned vo = (unsigned)((wave * 16 * NP + p0 + lane) * 4);
    const float* qb = qproj + (size_t)b * KMS;

    // prologue: q (oldest 16) + stages 0,1 in flight = 48 outstanding
    LD16(qr, vo, qb);
    LD16(kA, vo, KBASE(0));
    LD16(kB, vo, KBASE(1));
    // steady state: wait<=16 retires (q+stage m), FMA stage m, issue m+2
    STG(0, kA)  STG(1, kB)  STG(2, kA)  STG(3, kB)  STG(4, kA)  STG(5, kB)
    STG(6, kA)  STG(7, kB)  STG(8, kA)  STG(9, kB)  STG(10, kA) STG(11, kB)
    STG(12, kA) STG(13, kB) STG(14, kA) STG(15, kB) STG(16, kA) STG(17, kB)
    STG(18, kA) STG(19, kB) STG(20, kA) STG(21, kB) STG(22, kA) STG(23, kB)
    STG(24, kA) STG(25, kB) STG(26, kA) STG(27, kB) STG(28, kA) STG(29, kB)
    KWAIT16; FMA16(30, kA);
    KWAIT0;  FMA16(31, kB);

    // fold 16 es-partials -> 8 LDS slots [8][32][64]
    if (wave < 8) {
        #pragma unroll
        for (int m = 0; m < 32; ++m) smem[wave * 2048 + m * 64 + lane] = acc[m];
    }
    __syncthreads();
    if (wave >= 8) {
        #pragma unroll
        for (int m = 0; m < 32; ++m) smem[(wave - 8) * 2048 + m * 64 + lane] += acc[m];
    }
    __syncthreads();

    // softmax over w: wave handles rows {2*wave, 2*wave+1}; lane = w
    float att[2];
    #pragma unroll
    for (int r = 0; r < 2; ++r) {
        int m = wave * 2 + r;
        float x = 0.f;
        #pragma unroll
        for (int s = 0; s < 8; ++s) x += smem[s * 2048 + m * 64 + lane];
        x *= scale;
        float mx = x;
        #pragma unroll
        for (int d = 1; d < 64; d <<= 1) mx = fmaxf(mx, __shfl_xor(mx, d));
        float ev = __expf(x - mx);
        float sum = ev;
        #pragma unroll
        for (int d = 1; d < 64; d <<= 1) sum += __shfl_xor(sum, d);
        att[r] = ev / sum;
    }
    __syncthreads();                           // all slot reads done
    smem[(wave * 2) * 64 + lane] = att[0];     // attn[m][w] at offset 0
    smem[(wave * 2 + 1) * 64 + lane] = att[1];
    __syncthreads();

    // phase 3: ctx. wave=(mh=wave>>3, dq=wave&7); lane=(di=lane>>4, wg).
    {
        int di = lane >> 4;
        int mh = wave >> 3, dq = wave & 7;
        int dd = dq * 4 + di;
        f32x4 c4 = {0.f, 0.f, 0.f, 0.f};
        #pragma unroll
        for (int mm = 0; mm < 16; ++mm) {
            int m = mh * 16 + mm;
            const float* vb_ = (m < 4 ? vproj + (long)m * DVc * NP
                                      : vbuf + (long)(m - 4) * DVc * NP);
            f32x4 a4 = *reinterpret_cast<const f32x4*>(&smem[m * 64 + wg * 4]);
            f32x4 v4 = *reinterpret_cast<const f32x4*>(vb_ + (long)dd * NP + p0 + wg * 4);
            c4 += a4 * v4;
        }
        *reinterpret_cast<f32x4*>(&smem[4096 + mh * 2048 + dd * 64 + wg * 4]) = c4;
    }
    __syncthreads();

    // final: 2048 outputs / 1024 threads
    #pragma unroll
    for (int r = 0; r < 2; ++r) {
        int i = t + 1024 * r;
        int dd2 = i >> 6, w2 = i & 63;
        float c = smem[4096 + dd2 * 64 + w2] + smem[4096 + 2048 + dd2 * 64 + w2];
        long gi = ((long)b * DVc + dd2) * NP + p0 + w2;
        out[gi] = fm[gi] + 0.5f * c;
    }
}

extern "C" void kernel_launch(void* const* d_in, const int* in_sizes, int n_in,
                              void* d_out, int out_size, void* d_ws, size_t ws_size,
                              hipStream_t stream) {
    const float* fc = (const float*)d_in[0];
    const float* fm = (const float*)d_in[1];
    const float* kb = (const float*)d_in[2];
    const float* vb = (const float*)d_in[3];
    const float* Q  = (const float*)d_in[4];
    const float* K  = (const float*)d_in[5];
    const float* V  = (const float*)d_in[6];
    float* out = (float*)d_out;
    char* ws = (char*)d_ws;
    // layout: qproj/kproj/vproj persistent; fcT+WT dead after k_proj.
    float*          qproj = (float*)(ws);                          // 16777216 B
    float*          kproj = (float*)(ws + 16777216);               // 16777216 B
    float*          vproj = (float*)(ws + 33554432);               //  2097152 B
    unsigned short* fcT   = (unsigned short*)(ws + 35651584);      //  8388608 B
    unsigned short* WTq   = (unsigned short*)(ws + 44040192);      //   131072 B
    unsigned short* WTk   = (unsigned short*)(ws + 44171264);      //   131072 B
    float scale = (float)(log(135168.0) / log(1000.0) / 16.0);

    hipLaunchKernelGGL(k_prep, dim3(1120), dim3(256), 0, stream,
                       fc, fcT, Q, WTq, K, WTk, fm, V, vproj);
    hipLaunchKernelGGL(k_proj, dim3(64, 8), dim3(256), 0, stream,
                       WTq, WTk, fcT, qproj, kproj);
    hipLaunchKernelGGL(k_fused, dim3(256), dim3(1024), 0, stream,
                       qproj, kproj, kb, vproj, vb, fm, out, scale);
}